// Round 5
// baseline (244.155 us; speedup 1.0000x reference)
//
#include <hip/hip_runtime.h>

typedef unsigned short u16;
typedef unsigned int u32;
typedef short short8 __attribute__((ext_vector_type(8)));
typedef short short4v __attribute__((ext_vector_type(4)));
typedef float f32x4 __attribute__((ext_vector_type(4)));

#define EPS 1e-3f
#define C1F 0.18033688011112042f   // 0.125 * log2(e), folded into wk/bk in prep

// 16x16x16 bf16 MFMA (A/B = 4 bf16 per lane). Builtin only exists in the
// device pass; host pass just needs the expression to type-check.
#if defined(__HIP_DEVICE_COMPILE__)
#define MFMA16(a, b, c) __builtin_amdgcn_mfma_f32_16x16x16bf16_1k(a, b, c, 0, 0, 0)
#else
#define MFMA16(a, b, c) (c)
#endif

static __device__ __forceinline__ u16 f2bf(float f) {
    u32 u = __float_as_uint(f);
    u += 0x7fffu + ((u >> 16) & 1u);   // round-to-nearest-even
    return (u16)(u >> 16);
}
static __device__ __forceinline__ float bf2f(u16 v) {
    u32 u = (u32)v << 16;
    return __uint_as_float(u);
}
// pack two floats to bf16 pair: low half = a, high half = b
static __device__ __forceinline__ u32 pack_bf2(float a, float b) {
    u32 ua = __float_as_uint(a) + 0x8000u;
    u32 ub = __float_as_uint(b) + 0x8000u;
    return __builtin_amdgcn_perm(ub, ua, 0x07060302u);
}
static __device__ __forceinline__ void async_cp16(const void* g, void* l) {
    __builtin_amdgcn_global_load_lds(
        (const __attribute__((address_space(1))) unsigned int*)g,
        (__attribute__((address_space(3))) unsigned int*)l, 16, 0, 0);
}

// ---------------------------------------------------------------------------
// prep: wqkv concat -> bf16 [768][256] (k-cols pre-scaled C1); wo/w1/w2 -> bf16
// [N][K]; bqkv concat; bn scale/shift
// ---------------------------------------------------------------------------
__global__ void prep_kernel(const float* __restrict__ wq, const float* __restrict__ wk,
                            const float* __restrict__ wv, const float* __restrict__ wo,
                            const float* __restrict__ w1, const float* __restrict__ w2,
                            const float* __restrict__ bq, const float* __restrict__ bk,
                            const float* __restrict__ bv,
                            const float* __restrict__ g1, const float* __restrict__ b1,
                            const float* __restrict__ m1, const float* __restrict__ v1,
                            const float* __restrict__ g2, const float* __restrict__ b2,
                            const float* __restrict__ m2, const float* __restrict__ v2,
                            u16* __restrict__ wqkvT, u16* __restrict__ woT,
                            u16* __restrict__ w1T, u16* __restrict__ w2T,
                            float* __restrict__ bqkv,
                            float* __restrict__ bn1sc, float* __restrict__ bn1sh,
                            float* __restrict__ bn2sc, float* __restrict__ bn2sh) {
    int idx = blockIdx.x * 256 + threadIdx.x;
    if (idx < 196608) {                       // wqkvT [768][256]
        int n = idx >> 8, k = idx & 255;
        float v;
        if (n < 256)      v = wq[k * 256 + n];
        else if (n < 512) v = wk[k * 256 + (n - 256)] * C1F;
        else              v = wv[k * 256 + (n - 512)];
        wqkvT[idx] = f2bf(v);
    } else if (idx < 262144) {                // woT [256][256]
        int i = idx - 196608; int n = i >> 8, k = i & 255;
        woT[i] = f2bf(wo[k * 256 + n]);
    } else if (idx < 524288) {                // w1T [1024][256]
        int i = idx - 262144; int n = i >> 8, k = i & 255;
        w1T[i] = f2bf(w1[k * 1024 + n]);
    } else if (idx < 786432) {                // w2T [256][1024]
        int i = idx - 524288; int n = i >> 10, k = i & 1023;
        w2T[i] = f2bf(w2[k * 256 + n]);
    } else if (idx < 787200) {                // bqkv [768]
        int i = idx - 786432;
        bqkv[i] = (i < 256) ? bq[i] : (i < 512 ? bk[i - 256] * C1F : bv[i - 512]);
    } else if (idx < 787456) {                // bn1 sc/sh
        int i = idx - 787200;
        float sc = g1[i] * rsqrtf(v1[i] + EPS);
        bn1sc[i] = sc; bn1sh[i] = b1[i] - m1[i] * sc;
    } else if (idx < 787712) {                // bn2 sc/sh
        int i = idx - 787456;
        float sc = g2[i] * rsqrtf(v2[i] + EPS);
        bn2sc[i] = sc; bn2sh[i] = b2[i] - m2[i] * sc;
    }
}

// ---------------------------------------------------------------------------
// bn1: h = bn1(x) -> bf16 [8192][256]
// ---------------------------------------------------------------------------
__global__ void bn1_kernel(const float* __restrict__ x, const float* __restrict__ sc,
                           const float* __restrict__ sh, u16* __restrict__ h) {
    int idx = blockIdx.x * 256 + threadIdx.x;
    int base = idx * 4;
    int c = base & 255;
    float4 xv = *(const float4*)(x + base);
    float4 s4 = *(const float4*)(sc + c);
    float4 h4 = *(const float4*)(sh + c);
    ushort4 pk;
    pk.x = f2bf(fmaf(xv.x, s4.x, h4.x));
    pk.y = f2bf(fmaf(xv.y, s4.y, h4.y));
    pk.z = f2bf(fmaf(xv.z, s4.z, h4.z));
    pk.w = f2bf(fmaf(xv.w, s4.w, h4.w));
    *(ushort4*)(h + base) = pk;
}

// ---------------------------------------------------------------------------
// Barrier-free GEMM: C[M,N] = A[M,K] @ Bt[N,K]^T. No LDS; A/B frags straight
// from global (L1/L2 resident). WG = 4 waves; wave = MT*16 rows x 64 cols.
// EPI 0: qkv   (col<512: +bias->qkb row-major; col>=512: +bias->vT transposed)
// EPI 1: +bias+resid->f32 x1 AND bn2->bf16 h2
// EPI 2: gelu->bf16 | EPI 3: +resid->f32
// ---------------------------------------------------------------------------
template <int EPI, int MT>
__global__ __launch_bounds__(256) void gemm_nb(
        const u16* __restrict__ A, const u16* __restrict__ Bt,
        int M, int N, int K,
        const float* __restrict__ bias, const float* __restrict__ resid,
        float* __restrict__ out_f32, u16* __restrict__ out_bf,
        u16* __restrict__ out_vt,
        const float* __restrict__ b2sc, const float* __restrict__ b2sh) {
    const int t = threadIdx.x;
    const int w = t >> 6, lane = t & 63;
    const int l = lane & 15, Q = lane >> 4;
    const int m0 = blockIdx.x * (MT * 64) + w * (MT * 16);
    const int n0 = blockIdx.y * 64;

    const u16* Ab = A + (size_t)(m0 + l) * K + Q * 8;
    const u16* Bb = Bt + (size_t)(n0 + l) * K + Q * 8;

    f32x4 acc[MT][4];
#pragma unroll
    for (int mt = 0; mt < MT; ++mt)
#pragma unroll
        for (int nt = 0; nt < 4; ++nt) acc[mt][nt] = (f32x4){0.f, 0.f, 0.f, 0.f};

    const int K32 = K >> 5;
#pragma unroll 4
    for (int kd = 0; kd < K32; ++kd) {
        short8 bfr[4];
#pragma unroll
        for (int nt = 0; nt < 4; ++nt)
            bfr[nt] = *(const short8*)(Bb + (size_t)(nt * 16) * K + kd * 32);
#pragma unroll
        for (int mt = 0; mt < MT; ++mt) {
            short8 afr = *(const short8*)(Ab + (size_t)(mt * 16) * K + kd * 32);
#pragma unroll
            for (int nt = 0; nt < 4; ++nt)
                acc[mt][nt] = __builtin_amdgcn_mfma_f32_16x16x32_bf16(afr, bfr[nt], acc[mt][nt], 0, 0, 0);
        }
    }

#pragma unroll
    for (int mt = 0; mt < MT; ++mt)
#pragma unroll
        for (int nt = 0; nt < 4; ++nt) {
            int col = n0 + nt * 16 + l;
            int row0 = m0 + mt * 16 + Q * 4;
            if (EPI == 0) {
                float b = bias[col];
                if (col < 512) {
#pragma unroll
                    for (int r = 0; r < 4; ++r)
                        out_bf[(size_t)(row0 + r) * 512 + col] = f2bf(acc[mt][nt][r] + b);
                } else {
                    ushort4 pk;
                    pk.x = f2bf(acc[mt][nt][0] + b);
                    pk.y = f2bf(acc[mt][nt][1] + b);
                    pk.z = f2bf(acc[mt][nt][2] + b);
                    pk.w = f2bf(acc[mt][nt][3] + b);
                    *(ushort4*)(out_vt + (size_t)(col - 512) * 8192 + row0) = pk;
                }
            } else {
#pragma unroll
                for (int r = 0; r < 4; ++r) {
                    int row = row0 + r;
                    float val = acc[mt][nt][r];
                    size_t oidx = (size_t)row * N + col;
                    if (EPI == 1) {
                        val += bias[col] + resid[oidx];
                        out_f32[oidx] = val;
                        out_bf[oidx] = f2bf(fmaf(val, b2sc[col], b2sh[col]));
                    } else if (EPI == 2) {
                        float gl = 0.5f * val * (1.f + erff(val * 0.70710678118654752f));
                        out_bf[oidx] = f2bf(gl);
                    } else {
                        out_f32[oidx] = val + resid[oidx];
                    }
                }
            }
        }
}

// ---------------------------------------------------------------------------
// Flash attention v4: S^T form, no-max softmax, P^T -> PV via 16x16x16 MFMA
// identity layout (no LDS P, no shuffles). K/V double-buffered in LDS (32 KB).
// Wave = 32 q; WG = 128 q; grid (16 qt, 16 bh, 4 sp). bf16 partials.
// ---------------------------------------------------------------------------
static __device__ __forceinline__ void stage_tiles(const u16* kglob, const u16* vglob,
                                                   u16* kdst, u16* vdst,
                                                   int w, int lane, int kt) {
#pragma unroll
    for (int j = 0; j < 2; ++j) {
        int cw = (w * 2 + j) * 64 + lane;     // chunk 0..511
        int r = cw >> 3;                       // tile row 0..63
        int c = (cw & 7) ^ (r & 7);            // swizzled source chunk
        async_cp16(kglob + ((size_t)(kt * 64 + r)) * 512 + c * 8, kdst + (w * 2 + j) * 512);
        async_cp16(vglob + ((size_t)r) * 8192 + kt * 64 + c * 8, vdst + (w * 2 + j) * 512);
    }
}

__global__ __launch_bounds__(256) void attn_kernel(const u16* __restrict__ qk,
                                                   const u16* __restrict__ vT,
                                                   u16* __restrict__ opart,
                                                   float* __restrict__ lpart) {
    __shared__ u16 kbuf[2][4096];     // 64x64 bf16, 8-chunk XOR swizzle
    __shared__ u16 vbuf[2][4096];
    const int t = threadIdx.x;
    const int w = t >> 6, lane = t & 63;
    const int l = lane & 15, Q = lane >> 4;
    const int qt = blockIdx.x;        // 0..15
    const int bh = blockIdx.y;        // 0..15
    const int sp = blockIdx.z;        // 0..3 (512 s each)
    const int bb = bh >> 2, hd = bh & 3;
    const size_t rowbase = (size_t)bb * 2048;
    const int q0 = qt * 128 + w * 32;

    // Q B-frags (16x16x32), held for whole loop
    short8 qf[2][2];
#pragma unroll
    for (int qg = 0; qg < 2; ++qg)
#pragma unroll
        for (int kd = 0; kd < 2; ++kd)
            qf[qg][kd] = *(const short8*)(qk + (rowbase + q0 + qg * 16 + l) * 512
                                          + hd * 64 + kd * 32 + Q * 8);

    f32x4 o[2][4];
#pragma unroll
    for (int qg = 0; qg < 2; ++qg)
#pragma unroll
        for (int dt = 0; dt < 4; ++dt) o[qg][dt] = (f32x4){0.f, 0.f, 0.f, 0.f};
    float lacc[2] = {0.f, 0.f};

    const u16* kglob = qk + (rowbase + sp * 512) * 512 + 256 + hd * 64;      // row stride 512
    const u16* vglob = vT + ((size_t)(hd * 64)) * 8192 + rowbase + sp * 512; // row stride 8192

    stage_tiles(kglob, vglob, kbuf[0], vbuf[0], w, lane, 0);

    for (int kt = 0; kt < 8; ++kt) {
        __syncthreads();              // drains vmcnt: tile kt ready
        if (kt < 7)
            stage_tiles(kglob, vglob, kbuf[(kt + 1) & 1], vbuf[(kt + 1) & 1], w, lane, kt + 1);
        const u16* kb = kbuf[kt & 1];
        const u16* vb = vbuf[kt & 1];

        // S^T = K.Q^T -> exp2 -> pack. pf[qg][st] = B-frag for 16x16x16 PV.
        union { u32 u[2]; short4v s4; } pf[2][4];
#pragma unroll
        for (int st = 0; st < 4; ++st) {
            int r = st * 16 + l;
            short8 kf0 = *(const short8*)(kb + r * 64 + ((Q) ^ (r & 7)) * 8);
            short8 kf1 = *(const short8*)(kb + r * 64 + ((4 + Q) ^ (r & 7)) * 8);
#pragma unroll
            for (int qg = 0; qg < 2; ++qg) {
                f32x4 s = (f32x4){0.f, 0.f, 0.f, 0.f};
                s = __builtin_amdgcn_mfma_f32_16x16x32_bf16(kf0, qf[qg][0], s, 0, 0, 0);
                s = __builtin_amdgcn_mfma_f32_16x16x32_bf16(kf1, qf[qg][1], s, 0, 0, 0);
                float p0 = exp2f(fminf(s[0], 100.f));
                float p1 = exp2f(fminf(s[1], 100.f));
                float p2 = exp2f(fminf(s[2], 100.f));
                float p3 = exp2f(fminf(s[3], 100.f));
                lacc[qg] += (p0 + p1) + (p2 + p3);
                pf[qg][st].u[0] = pack_bf2(p0, p1);
                pf[qg][st].u[1] = pack_bf2(p2, p3);
            }
        }

        // O^T += V^T . P^T : 4 chunks of K=16, A = V^T from LDS (b64),
        // B = pf (identity C->B layout for 16x16x16)
#pragma unroll
        for (int c = 0; c < 4; ++c) {
#pragma unroll
            for (int dt = 0; dt < 4; ++dt) {
                int r = dt * 16 + l;
                int slot = (2 * c + (Q >> 1)) ^ (r & 7);
                short4v vf = *(const short4v*)(vb + r * 64 + slot * 8 + (Q & 1) * 4);
                o[0][dt] = MFMA16(vf, pf[0][c].s4, o[0][dt]);
                o[1][dt] = MFMA16(vf, pf[1][c].s4, o[1][dt]);
            }
        }
    }

    // epilogue: reduce l across quads; bf16 partials
#pragma unroll
    for (int qg = 0; qg < 2; ++qg) {
        float v = lacc[qg];
        v += __shfl_xor(v, 16);
        v += __shfl_xor(v, 32);
        lacc[qg] = v;
    }
    u16* ob = opart + (((size_t)sp * 16 + bh) * 2048 + q0) * 64;
#pragma unroll
    for (int qg = 0; qg < 2; ++qg)
#pragma unroll
        for (int dt = 0; dt < 4; ++dt) {
            ushort4 pk;
            pk.x = f2bf(o[qg][dt][0]);
            pk.y = f2bf(o[qg][dt][1]);
            pk.z = f2bf(o[qg][dt][2]);
            pk.w = f2bf(o[qg][dt][3]);
            *(ushort4*)(ob + (size_t)(qg * 16 + l) * 64 + dt * 16 + Q * 4) = pk;
        }
    if (Q == 0) {
        size_t lb = ((size_t)sp * 16 + bh) * 2048 + q0;
        lpart[lb + l] = lacc[0];
        lpart[lb + 16 + l] = lacc[1];
    }
}

// ---------------------------------------------------------------------------
// combine: ctx[b*2048+s][h*64+d] = sum_sp(o_sp) / sum_sp(l_sp) -> bf16
// ---------------------------------------------------------------------------
__global__ void combine_kernel(const u16* __restrict__ opart,
                               const float* __restrict__ lpart,
                               u16* __restrict__ ctx) {
    int idx = blockIdx.x * 256 + threadIdx.x;
    int e = idx * 4;
    int row = e >> 8, col = e & 255;
    int b = row >> 11, s = row & 2047, h = col >> 6, d = col & 63;
    float a0 = 0.f, a1 = 0.f, a2 = 0.f, a3 = 0.f, lsum = 0.f;
#pragma unroll
    for (int sp = 0; sp < 4; ++sp) {
        size_t pb = (((size_t)sp * 16 + b * 4 + h) * 2048 + s) * 64 + d;
        ushort4 ov = *(const ushort4*)(opart + pb);
        a0 += bf2f(ov.x); a1 += bf2f(ov.y); a2 += bf2f(ov.z); a3 += bf2f(ov.w);
        lsum += lpart[((size_t)sp * 16 + b * 4 + h) * 2048 + s];
    }
    float li = 1.0f / lsum;
    ushort4 pk;
    pk.x = f2bf(a0 * li);
    pk.y = f2bf(a1 * li);
    pk.z = f2bf(a2 * li);
    pk.w = f2bf(a3 * li);
    *(ushort4*)(ctx + e) = pk;
}

// ---------------------------------------------------------------------------
extern "C" void kernel_launch(void* const* d_in, const int* in_sizes, int n_in,
                              void* d_out, int out_size, void* d_ws, size_t ws_size,
                              hipStream_t stream) {
    (void)in_sizes; (void)n_in; (void)out_size; (void)ws_size;
    const float* x  = (const float*)d_in[0];
    const float* g1 = (const float*)d_in[1];
    const float* b1 = (const float*)d_in[2];
    const float* m1 = (const float*)d_in[3];
    const float* v1 = (const float*)d_in[4];
    const float* wq = (const float*)d_in[5];
    const float* bq = (const float*)d_in[6];
    const float* wk = (const float*)d_in[7];
    const float* bk = (const float*)d_in[8];
    const float* wv = (const float*)d_in[9];
    const float* bv = (const float*)d_in[10];
    const float* wo = (const float*)d_in[11];
    const float* bo = (const float*)d_in[12];
    const float* g2 = (const float*)d_in[13];
    const float* b2 = (const float*)d_in[14];
    const float* m2 = (const float*)d_in[15];
    const float* v2 = (const float*)d_in[16];
    const float* w1 = (const float*)d_in[17];
    const float* w2 = (const float*)d_in[18];

    char* ws = (char*)d_ws;
    u16*   qkb    = (u16*)(ws + 0);            // [8192][512] bf16, 8 MB
    u16*   ctxh   = (u16*)(ws + 8388608);      // h (bn1) then ctx, [8192][256] bf16, 4 MB
    float* x1     = (float*)(ws + 12582912);   // [8192][256] f32, 8 MB (lpart overlays)
    float* lpart  = (float*)(ws + 12582912);   // [4][16][2048] f32, 512 KB (dead before x1 written)
    u16*   h2     = (u16*)(ws + 20971520);     // [8192][256] bf16, 4 MB
    u16*   opart  = (u16*)(ws + 25165824);     // [4][16][2048][64] bf16, 16 MB
    u16*   gbuf   = (u16*)(ws + 25165824);     // [8192][1024] bf16 overlays opart after combine
    u16*   vTb    = (u16*)(ws + 41943040);     // [256][8192] bf16, 4 MB
    u16*   wqkvT  = (u16*)(ws + 46137344);     // [768][256] bf16
    u16*   woT    = (u16*)(ws + 46530560);     // [256][256]
    u16*   w1T    = (u16*)(ws + 46661632);     // [1024][256]
    u16*   w2T    = (u16*)(ws + 47185920);     // [256][1024]
    float* bqkv   = (float*)(ws + 47710208);   // [768]
    float* bn1sc  = (float*)(ws + 47713280);
    float* bn1sh  = (float*)(ws + 47714304);
    float* bn2sc  = (float*)(ws + 47715328);
    float* bn2sh  = (float*)(ws + 47716352);
    u16*   h_buf  = ctxh;
    u16*   ctx    = ctxh;
    float* out    = (float*)d_out;

    prep_kernel<<<3077, 256, 0, stream>>>(wq, wk, wv, wo, w1, w2, bq, bk, bv,
                                          g1, b1, m1, v1, g2, b2, m2, v2,
                                          wqkvT, woT, w1T, w2T, bqkv,
                                          bn1sc, bn1sh, bn2sc, bn2sh);
    bn1_kernel<<<2048, 256, 0, stream>>>(x, bn1sc, bn1sh, h_buf);
    // QKV projection (q|k row-major into qkb; v transposed into vTb)
    gemm_nb<0, 2><<<dim3(64, 12), 256, 0, stream>>>(
        h_buf, wqkvT, 8192, 768, 256, bqkv, nullptr, nullptr, qkb, vTb, nullptr, nullptr);
    // attention partials + combine
    attn_kernel<<<dim3(16, 16, 4), 256, 0, stream>>>(qkb, vTb, opart, lpart);
    combine_kernel<<<2048, 256, 0, stream>>>(opart, lpart, ctx);
    // O projection + residual + bn2
    gemm_nb<1, 1><<<dim3(128, 4), 256, 0, stream>>>(
        ctx, woT, 8192, 256, 256, bo, x, x1, h2, nullptr, bn2sc, bn2sh);
    // FFN1 + gelu
    gemm_nb<2, 2><<<dim3(64, 16), 256, 0, stream>>>(
        h2, w1T, 8192, 1024, 256, nullptr, nullptr, nullptr, gbuf, nullptr, nullptr, nullptr);
    // FFN2 + residual -> out
    gemm_nb<3, 1><<<dim3(128, 4), 256, 0, stream>>>(
        gbuf, w2T, 8192, 256, 1024, nullptr, x1, out, nullptr, nullptr, nullptr, nullptr);
}

// Round 6
// 196.360 us; speedup vs baseline: 1.2434x; 1.2434x over previous
//
#include <hip/hip_runtime.h>

typedef unsigned short u16;
typedef unsigned int u32;
typedef short short8 __attribute__((ext_vector_type(8)));
typedef short short4v __attribute__((ext_vector_type(4)));
typedef float f32x4 __attribute__((ext_vector_type(4)));

#define EPS 1e-3f
#define C1F 0.18033688011112042f   // 0.125 * log2(e), folded into wk/bk in prep

// 16x16x16 bf16 MFMA (A/B = 4 bf16 per lane). Builtin only exists in the
// device pass; host pass just needs the expression to type-check.
#if defined(__HIP_DEVICE_COMPILE__)
#define MFMA16(a, b, c) __builtin_amdgcn_mfma_f32_16x16x16bf16_1k(a, b, c, 0, 0, 0)
#else
#define MFMA16(a, b, c) (c)
#endif

static __device__ __forceinline__ u16 f2bf(float f) {
    u32 u = __float_as_uint(f);
    u += 0x7fffu + ((u >> 16) & 1u);   // round-to-nearest-even
    return (u16)(u >> 16);
}
static __device__ __forceinline__ float bf2f(u16 v) {
    u32 u = (u32)v << 16;
    return __uint_as_float(u);
}
// pack two floats to bf16 pair: low half = a, high half = b
static __device__ __forceinline__ u32 pack_bf2(float a, float b) {
    u32 ua = __float_as_uint(a) + 0x8000u;
    u32 ub = __float_as_uint(b) + 0x8000u;
    return __builtin_amdgcn_perm(ub, ua, 0x07060302u);
}
static __device__ __forceinline__ void async_cp16(const void* g, void* l) {
    __builtin_amdgcn_global_load_lds(
        (const __attribute__((address_space(1))) unsigned int*)g,
        (__attribute__((address_space(3))) unsigned int*)l, 16, 0, 0);
}

// ---------------------------------------------------------------------------
// prep: wqkv concat -> bf16 [768][256] (k-cols pre-scaled C1); wo/w1/w2 -> bf16
// [N][K]; bqkv concat; bn scale/shift
// ---------------------------------------------------------------------------
__global__ void prep_kernel(const float* __restrict__ wq, const float* __restrict__ wk,
                            const float* __restrict__ wv, const float* __restrict__ wo,
                            const float* __restrict__ w1, const float* __restrict__ w2,
                            const float* __restrict__ bq, const float* __restrict__ bk,
                            const float* __restrict__ bv,
                            const float* __restrict__ g1, const float* __restrict__ b1,
                            const float* __restrict__ m1, const float* __restrict__ v1,
                            const float* __restrict__ g2, const float* __restrict__ b2,
                            const float* __restrict__ m2, const float* __restrict__ v2,
                            u16* __restrict__ wqkvT, u16* __restrict__ woT,
                            u16* __restrict__ w1T, u16* __restrict__ w2T,
                            float* __restrict__ bqkv,
                            float* __restrict__ bn1sc, float* __restrict__ bn1sh,
                            float* __restrict__ bn2sc, float* __restrict__ bn2sh) {
    int idx = blockIdx.x * 256 + threadIdx.x;
    if (idx < 196608) {                       // wqkvT [768][256]
        int n = idx >> 8, k = idx & 255;
        float v;
        if (n < 256)      v = wq[k * 256 + n];
        else if (n < 512) v = wk[k * 256 + (n - 256)] * C1F;
        else              v = wv[k * 256 + (n - 512)];
        wqkvT[idx] = f2bf(v);
    } else if (idx < 262144) {                // woT [256][256]
        int i = idx - 196608; int n = i >> 8, k = i & 255;
        woT[i] = f2bf(wo[k * 256 + n]);
    } else if (idx < 524288) {                // w1T [1024][256]
        int i = idx - 262144; int n = i >> 8, k = i & 255;
        w1T[i] = f2bf(w1[k * 1024 + n]);
    } else if (idx < 786432) {                // w2T [256][1024]
        int i = idx - 524288; int n = i >> 10, k = i & 1023;
        w2T[i] = f2bf(w2[k * 256 + n]);
    } else if (idx < 787200) {                // bqkv [768]
        int i = idx - 786432;
        bqkv[i] = (i < 256) ? bq[i] : (i < 512 ? bk[i - 256] * C1F : bv[i - 512]);
    } else if (idx < 787456) {                // bn1 sc/sh
        int i = idx - 787200;
        float sc = g1[i] * rsqrtf(v1[i] + EPS);
        bn1sc[i] = sc; bn1sh[i] = b1[i] - m1[i] * sc;
    } else if (idx < 787712) {                // bn2 sc/sh
        int i = idx - 787456;
        float sc = g2[i] * rsqrtf(v2[i] + EPS);
        bn2sc[i] = sc; bn2sh[i] = b2[i] - m2[i] * sc;
    }
}

// ---------------------------------------------------------------------------
// bn1: h = bn1(x) -> bf16 [8192][256]
// ---------------------------------------------------------------------------
__global__ void bn1_kernel(const float* __restrict__ x, const float* __restrict__ sc,
                           const float* __restrict__ sh, u16* __restrict__ h) {
    int idx = blockIdx.x * 256 + threadIdx.x;
    int base = idx * 4;
    int c = base & 255;
    float4 xv = *(const float4*)(x + base);
    float4 s4 = *(const float4*)(sc + c);
    float4 h4 = *(const float4*)(sh + c);
    ushort4 pk;
    pk.x = f2bf(fmaf(xv.x, s4.x, h4.x));
    pk.y = f2bf(fmaf(xv.y, s4.y, h4.y));
    pk.z = f2bf(fmaf(xv.z, s4.z, h4.z));
    pk.w = f2bf(fmaf(xv.w, s4.w, h4.w));
    *(ushort4*)(h + base) = pk;
}

// ---------------------------------------------------------------------------
// m97-style staged GEMM: C[M,N] = A[M,K] @ Bt[N,K]^T.
// Tile = (MT*32) x 128, BK=64, 4 waves; wave (w&1 = row half, w>>1 = col half)
// computes (MT*16) x 64. A and B tiles staged via global_load_lds width=16
// with XOR chunk swizzle; ds_read_b128 fragment reads.
// EPI 0: qkv (col<512: +bias->row-major; col>=512: +bias->vT transposed)
// EPI 1: +bias+resid->f32 x1 AND bn2->bf16 h2
// EPI 2: gelu->bf16 | EPI 3: +resid->f32
// ---------------------------------------------------------------------------
template <int EPI, int MT>
__global__ __launch_bounds__(256) void gemm_sd(
        const u16* __restrict__ A, const u16* __restrict__ Bt,
        int M, int N, int K,
        const float* __restrict__ bias, const float* __restrict__ resid,
        float* __restrict__ out_f32, u16* __restrict__ out_bf,
        u16* __restrict__ out_vt,
        const float* __restrict__ b2sc, const float* __restrict__ b2sh) {
    __shared__ u16 abuf[MT * 32 * 64];    // (MT*32) rows x 64 k, swizzled
    __shared__ u16 bbuf[128 * 64];        // 128 cols x 64 k, swizzled
    const int t = threadIdx.x;
    const int w = t >> 6, lane = t & 63;
    const int l = lane & 15, Q = lane >> 4;
    const int m0 = blockIdx.x * (MT * 32);
    const int n0 = blockIdx.y * 128;
    const int rowh = (w & 1) * (MT * 16);
    const int colh = (w >> 1) * 64;

    f32x4 acc[MT][4];
#pragma unroll
    for (int mt = 0; mt < MT; ++mt)
#pragma unroll
        for (int nt = 0; nt < 4; ++nt) acc[mt][nt] = (f32x4){0.f, 0.f, 0.f, 0.f};

    for (int k0 = 0; k0 < K; k0 += 64) {
        __syncthreads();
        // stage A tile: MT*256 chunks of 16B
#pragma unroll
        for (int j = 0; j < MT; ++j) {
            int idx = j * 256 + t;
            int r = idx >> 3, c8 = idx & 7;
            int sc = c8 ^ (r & 7);
            async_cp16(A + (size_t)(m0 + r) * K + k0 + sc * 8, abuf + idx * 8);
        }
        // stage B tile: 1024 chunks
#pragma unroll
        for (int j = 0; j < 4; ++j) {
            int idx = j * 256 + t;
            int r = idx >> 3, c8 = idx & 7;
            int sc = c8 ^ (r & 7);
            async_cp16(Bt + (size_t)(n0 + r) * K + k0 + sc * 8, bbuf + idx * 8);
        }
        __syncthreads();   // vmcnt drained: tile ready
#pragma unroll
        for (int kd = 0; kd < 2; ++kd) {
            short8 bfr[4];
#pragma unroll
            for (int nt = 0; nt < 4; ++nt) {
                int r = colh + nt * 16 + l;
                int slot = (kd * 4 + Q) ^ (r & 7);
                bfr[nt] = *(const short8*)(bbuf + r * 64 + slot * 8);
            }
#pragma unroll
            for (int mt = 0; mt < MT; ++mt) {
                int r = rowh + mt * 16 + l;
                int slot = (kd * 4 + Q) ^ (r & 7);
                short8 afr = *(const short8*)(abuf + r * 64 + slot * 8);
#pragma unroll
                for (int nt = 0; nt < 4; ++nt)
                    acc[mt][nt] = __builtin_amdgcn_mfma_f32_16x16x32_bf16(afr, bfr[nt], acc[mt][nt], 0, 0, 0);
            }
        }
    }

#pragma unroll
    for (int mt = 0; mt < MT; ++mt)
#pragma unroll
        for (int nt = 0; nt < 4; ++nt) {
            int col = n0 + colh + nt * 16 + l;
            int row0 = m0 + rowh + mt * 16 + Q * 4;
            if (EPI == 0) {
                float b = bias[col];
                if (col < 512) {
#pragma unroll
                    for (int r = 0; r < 4; ++r)
                        out_bf[(size_t)(row0 + r) * 512 + col] = f2bf(acc[mt][nt][r] + b);
                } else {
                    ushort4 pk;
                    pk.x = f2bf(acc[mt][nt][0] + b);
                    pk.y = f2bf(acc[mt][nt][1] + b);
                    pk.z = f2bf(acc[mt][nt][2] + b);
                    pk.w = f2bf(acc[mt][nt][3] + b);
                    *(ushort4*)(out_vt + (size_t)(col - 512) * 8192 + row0) = pk;
                }
            } else {
#pragma unroll
                for (int r = 0; r < 4; ++r) {
                    int row = row0 + r;
                    float val = acc[mt][nt][r];
                    size_t oidx = (size_t)row * N + col;
                    if (EPI == 1) {
                        val += bias[col] + resid[oidx];
                        out_f32[oidx] = val;
                        out_bf[oidx] = f2bf(fmaf(val, b2sc[col], b2sh[col]));
                    } else if (EPI == 2) {
                        float gl = 0.5f * val * (1.f + erff(val * 0.70710678118654752f));
                        out_bf[oidx] = f2bf(gl);
                    } else {
                        out_f32[oidx] = val + resid[oidx];
                    }
                }
            }
        }
}

// ---------------------------------------------------------------------------
// Flash attention v4 (unchanged from R5): S^T form, no-max softmax,
// P^T -> PV via 16x16x16 MFMA identity layout. K/V double-buffered in LDS.
// Wave = 32 q; WG = 128 q; grid (16 qt, 16 bh, 4 sp). bf16 partials.
// ---------------------------------------------------------------------------
static __device__ __forceinline__ void stage_tiles(const u16* kglob, const u16* vglob,
                                                   u16* kdst, u16* vdst,
                                                   int w, int lane, int kt) {
#pragma unroll
    for (int j = 0; j < 2; ++j) {
        int cw = (w * 2 + j) * 64 + lane;     // chunk 0..511
        int r = cw >> 3;                       // tile row 0..63
        int c = (cw & 7) ^ (r & 7);            // swizzled source chunk
        async_cp16(kglob + ((size_t)(kt * 64 + r)) * 512 + c * 8, kdst + (w * 2 + j) * 512);
        async_cp16(vglob + ((size_t)r) * 8192 + kt * 64 + c * 8, vdst + (w * 2 + j) * 512);
    }
}

__global__ __launch_bounds__(256) void attn_kernel(const u16* __restrict__ qk,
                                                   const u16* __restrict__ vT,
                                                   u16* __restrict__ opart,
                                                   float* __restrict__ lpart) {
    __shared__ u16 kbuf[2][4096];     // 64x64 bf16, 8-chunk XOR swizzle
    __shared__ u16 vbuf[2][4096];
    const int t = threadIdx.x;
    const int w = t >> 6, lane = t & 63;
    const int l = lane & 15, Q = lane >> 4;
    const int qt = blockIdx.x;        // 0..15
    const int bh = blockIdx.y;        // 0..15
    const int sp = blockIdx.z;        // 0..3 (512 s each)
    const int bb = bh >> 2, hd = bh & 3;
    const size_t rowbase = (size_t)bb * 2048;
    const int q0 = qt * 128 + w * 32;

    // Q B-frags (16x16x32), held for whole loop
    short8 qf[2][2];
#pragma unroll
    for (int qg = 0; qg < 2; ++qg)
#pragma unroll
        for (int kd = 0; kd < 2; ++kd)
            qf[qg][kd] = *(const short8*)(qk + (rowbase + q0 + qg * 16 + l) * 512
                                          + hd * 64 + kd * 32 + Q * 8);

    f32x4 o[2][4];
#pragma unroll
    for (int qg = 0; qg < 2; ++qg)
#pragma unroll
        for (int dt = 0; dt < 4; ++dt) o[qg][dt] = (f32x4){0.f, 0.f, 0.f, 0.f};
    float lacc[2] = {0.f, 0.f};

    const u16* kglob = qk + (rowbase + sp * 512) * 512 + 256 + hd * 64;      // row stride 512
    const u16* vglob = vT + ((size_t)(hd * 64)) * 8192 + rowbase + sp * 512; // row stride 8192

    stage_tiles(kglob, vglob, kbuf[0], vbuf[0], w, lane, 0);

    for (int kt = 0; kt < 8; ++kt) {
        __syncthreads();              // drains vmcnt: tile kt ready
        if (kt < 7)
            stage_tiles(kglob, vglob, kbuf[(kt + 1) & 1], vbuf[(kt + 1) & 1], w, lane, kt + 1);
        const u16* kb = kbuf[kt & 1];
        const u16* vb = vbuf[kt & 1];

        // S^T = K.Q^T -> exp2 -> pack. pf[qg][st] = B-frag for 16x16x16 PV.
        union { u32 u[2]; short4v s4; } pf[2][4];
#pragma unroll
        for (int st = 0; st < 4; ++st) {
            int r = st * 16 + l;
            short8 kf0 = *(const short8*)(kb + r * 64 + ((Q) ^ (r & 7)) * 8);
            short8 kf1 = *(const short8*)(kb + r * 64 + ((4 + Q) ^ (r & 7)) * 8);
#pragma unroll
            for (int qg = 0; qg < 2; ++qg) {
                f32x4 s = (f32x4){0.f, 0.f, 0.f, 0.f};
                s = __builtin_amdgcn_mfma_f32_16x16x32_bf16(kf0, qf[qg][0], s, 0, 0, 0);
                s = __builtin_amdgcn_mfma_f32_16x16x32_bf16(kf1, qf[qg][1], s, 0, 0, 0);
                float p0 = exp2f(fminf(s[0], 100.f));
                float p1 = exp2f(fminf(s[1], 100.f));
                float p2 = exp2f(fminf(s[2], 100.f));
                float p3 = exp2f(fminf(s[3], 100.f));
                lacc[qg] += (p0 + p1) + (p2 + p3);
                pf[qg][st].u[0] = pack_bf2(p0, p1);
                pf[qg][st].u[1] = pack_bf2(p2, p3);
            }
        }

        // O^T += V^T . P^T : 4 chunks of K=16, A = V^T from LDS (b64),
        // B = pf (identity C->B layout for 16x16x16)
#pragma unroll
        for (int c = 0; c < 4; ++c) {
#pragma unroll
            for (int dt = 0; dt < 4; ++dt) {
                int r = dt * 16 + l;
                int slot = (2 * c + (Q >> 1)) ^ (r & 7);
                short4v vf = *(const short4v*)(vb + r * 64 + slot * 8 + (Q & 1) * 4);
                o[0][dt] = MFMA16(vf, pf[0][c].s4, o[0][dt]);
                o[1][dt] = MFMA16(vf, pf[1][c].s4, o[1][dt]);
            }
        }
    }

    // epilogue: reduce l across quads; bf16 partials
#pragma unroll
    for (int qg = 0; qg < 2; ++qg) {
        float v = lacc[qg];
        v += __shfl_xor(v, 16);
        v += __shfl_xor(v, 32);
        lacc[qg] = v;
    }
    u16* ob = opart + (((size_t)sp * 16 + bh) * 2048 + q0) * 64;
#pragma unroll
    for (int qg = 0; qg < 2; ++qg)
#pragma unroll
        for (int dt = 0; dt < 4; ++dt) {
            ushort4 pk;
            pk.x = f2bf(o[qg][dt][0]);
            pk.y = f2bf(o[qg][dt][1]);
            pk.z = f2bf(o[qg][dt][2]);
            pk.w = f2bf(o[qg][dt][3]);
            *(ushort4*)(ob + (size_t)(qg * 16 + l) * 64 + dt * 16 + Q * 4) = pk;
        }
    if (Q == 0) {
        size_t lb = ((size_t)sp * 16 + bh) * 2048 + q0;
        lpart[lb + l] = lacc[0];
        lpart[lb + 16 + l] = lacc[1];
    }
}

// ---------------------------------------------------------------------------
// combine: ctx[b*2048+s][h*64+d] = sum_sp(o_sp) / sum_sp(l_sp) -> bf16
// ---------------------------------------------------------------------------
__global__ void combine_kernel(const u16* __restrict__ opart,
                               const float* __restrict__ lpart,
                               u16* __restrict__ ctx) {
    int idx = blockIdx.x * 256 + threadIdx.x;
    int e = idx * 4;
    int row = e >> 8, col = e & 255;
    int b = row >> 11, s = row & 2047, h = col >> 6, d = col & 63;
    float a0 = 0.f, a1 = 0.f, a2 = 0.f, a3 = 0.f, lsum = 0.f;
#pragma unroll
    for (int sp = 0; sp < 4; ++sp) {
        size_t pb = (((size_t)sp * 16 + b * 4 + h) * 2048 + s) * 64 + d;
        ushort4 ov = *(const ushort4*)(opart + pb);
        a0 += bf2f(ov.x); a1 += bf2f(ov.y); a2 += bf2f(ov.z); a3 += bf2f(ov.w);
        lsum += lpart[((size_t)sp * 16 + b * 4 + h) * 2048 + s];
    }
    float li = 1.0f / lsum;
    ushort4 pk;
    pk.x = f2bf(a0 * li);
    pk.y = f2bf(a1 * li);
    pk.z = f2bf(a2 * li);
    pk.w = f2bf(a3 * li);
    *(ushort4*)(ctx + e) = pk;
}

// ---------------------------------------------------------------------------
extern "C" void kernel_launch(void* const* d_in, const int* in_sizes, int n_in,
                              void* d_out, int out_size, void* d_ws, size_t ws_size,
                              hipStream_t stream) {
    (void)in_sizes; (void)n_in; (void)out_size; (void)ws_size;
    const float* x  = (const float*)d_in[0];
    const float* g1 = (const float*)d_in[1];
    const float* b1 = (const float*)d_in[2];
    const float* m1 = (const float*)d_in[3];
    const float* v1 = (const float*)d_in[4];
    const float* wq = (const float*)d_in[5];
    const float* bq = (const float*)d_in[6];
    const float* wk = (const float*)d_in[7];
    const float* bk = (const float*)d_in[8];
    const float* wv = (const float*)d_in[9];
    const float* bv = (const float*)d_in[10];
    const float* wo = (const float*)d_in[11];
    const float* bo = (const float*)d_in[12];
    const float* g2 = (const float*)d_in[13];
    const float* b2 = (const float*)d_in[14];
    const float* m2 = (const float*)d_in[15];
    const float* v2 = (const float*)d_in[16];
    const float* w1 = (const float*)d_in[17];
    const float* w2 = (const float*)d_in[18];

    char* ws = (char*)d_ws;
    u16*   qkb    = (u16*)(ws + 0);            // [8192][512] bf16, 8 MB
    u16*   ctxh   = (u16*)(ws + 8388608);      // h (bn1) then ctx, [8192][256] bf16, 4 MB
    float* x1     = (float*)(ws + 12582912);   // [8192][256] f32, 8 MB (lpart overlays)
    float* lpart  = (float*)(ws + 12582912);   // [4][16][2048] f32 (dead before x1 written)
    u16*   h2     = (u16*)(ws + 20971520);     // [8192][256] bf16, 4 MB
    u16*   opart  = (u16*)(ws + 25165824);     // [4][16][2048][64] bf16, 16 MB
    u16*   gbuf   = (u16*)(ws + 25165824);     // [8192][1024] bf16 overlays opart after combine
    u16*   vTb    = (u16*)(ws + 41943040);     // [256][8192] bf16, 4 MB
    u16*   wqkvT  = (u16*)(ws + 46137344);     // [768][256] bf16
    u16*   woT    = (u16*)(ws + 46530560);     // [256][256]
    u16*   w1T    = (u16*)(ws + 46661632);     // [1024][256]
    u16*   w2T    = (u16*)(ws + 47185920);     // [256][1024]
    float* bqkv   = (float*)(ws + 47710208);   // [768]
    float* bn1sc  = (float*)(ws + 47713280);
    float* bn1sh  = (float*)(ws + 47714304);
    float* bn2sc  = (float*)(ws + 47715328);
    float* bn2sh  = (float*)(ws + 47716352);
    u16*   h_buf  = ctxh;
    u16*   ctx    = ctxh;
    float* out    = (float*)d_out;

    prep_kernel<<<3077, 256, 0, stream>>>(wq, wk, wv, wo, w1, w2, bq, bk, bv,
                                          g1, b1, m1, v1, g2, b2, m2, v2,
                                          wqkvT, woT, w1T, w2T, bqkv,
                                          bn1sc, bn1sh, bn2sc, bn2sh);
    bn1_kernel<<<2048, 256, 0, stream>>>(x, bn1sc, bn1sh, h_buf);
    // QKV projection (q|k row-major into qkb; v transposed into vTb), 128x128 tiles
    gemm_sd<0, 4><<<dim3(64, 6), 256, 0, stream>>>(
        h_buf, wqkvT, 8192, 768, 256, bqkv, nullptr, nullptr, qkb, vTb, nullptr, nullptr);
    // attention partials + combine
    attn_kernel<<<dim3(16, 16, 4), 256, 0, stream>>>(qkb, vTb, opart, lpart);
    combine_kernel<<<2048, 256, 0, stream>>>(opart, lpart, ctx);
    // O projection + residual + bn2, 64x128 tiles
    gemm_sd<1, 2><<<dim3(128, 2), 256, 0, stream>>>(
        ctx, woT, 8192, 256, 256, bo, x, x1, h2, nullptr, bn2sc, bn2sh);
    // FFN1 + gelu, 128x128 tiles
    gemm_sd<2, 4><<<dim3(64, 8), 256, 0, stream>>>(
        h2, w1T, 8192, 1024, 256, nullptr, nullptr, nullptr, gbuf, nullptr, nullptr, nullptr);
    // FFN2 + residual -> out, 64x128 tiles, K=1024
    gemm_sd<3, 2><<<dim3(128, 2), 256, 0, stream>>>(
        gbuf, w2T, 8192, 256, 1024, nullptr, x1, out, nullptr, nullptr, nullptr, nullptr);
}

// Round 7
// 193.190 us; speedup vs baseline: 1.2638x; 1.0164x over previous
//
#include <hip/hip_runtime.h>

typedef unsigned short u16;
typedef unsigned int u32;
typedef short short8 __attribute__((ext_vector_type(8)));
typedef short short4v __attribute__((ext_vector_type(4)));
typedef float f32x4 __attribute__((ext_vector_type(4)));

#define EPS 1e-3f
#define C1F 0.18033688011112042f   // 0.125 * log2(e), folded into wk/bk in prep

// 16x16x16 bf16 MFMA (A/B = 4 bf16 per lane). Builtin only exists in the
// device pass; host pass just needs the expression to type-check.
#if defined(__HIP_DEVICE_COMPILE__)
#define MFMA16(a, b, c) __builtin_amdgcn_mfma_f32_16x16x16bf16_1k(a, b, c, 0, 0, 0)
#else
#define MFMA16(a, b, c) (c)
#endif

static __device__ __forceinline__ u16 f2bf(float f) {
    u32 u = __float_as_uint(f);
    u += 0x7fffu + ((u >> 16) & 1u);   // round-to-nearest-even
    return (u16)(u >> 16);
}
static __device__ __forceinline__ float bf2f(u16 v) {
    u32 u = (u32)v << 16;
    return __uint_as_float(u);
}
// pack two floats to bf16 pair: low half = a, high half = b
static __device__ __forceinline__ u32 pack_bf2(float a, float b) {
    u32 ua = __float_as_uint(a) + 0x8000u;
    u32 ub = __float_as_uint(b) + 0x8000u;
    return __builtin_amdgcn_perm(ub, ua, 0x07060302u);
}
static __device__ __forceinline__ void async_cp16(const void* g, void* l) {
    __builtin_amdgcn_global_load_lds(
        (const __attribute__((address_space(1))) unsigned int*)g,
        (__attribute__((address_space(3))) unsigned int*)l, 16, 0, 0);
}

// ---------------------------------------------------------------------------
// prep: wqkv concat -> bf16 [768][256] (k-cols pre-scaled C1); wo/w1/w2 -> bf16
// [N][K]; bqkv concat; bn scale/shift
// ---------------------------------------------------------------------------
__global__ void prep_kernel(const float* __restrict__ wq, const float* __restrict__ wk,
                            const float* __restrict__ wv, const float* __restrict__ wo,
                            const float* __restrict__ w1, const float* __restrict__ w2,
                            const float* __restrict__ bq, const float* __restrict__ bk,
                            const float* __restrict__ bv,
                            const float* __restrict__ g1, const float* __restrict__ b1,
                            const float* __restrict__ m1, const float* __restrict__ v1,
                            const float* __restrict__ g2, const float* __restrict__ b2,
                            const float* __restrict__ m2, const float* __restrict__ v2,
                            u16* __restrict__ wqkvT, u16* __restrict__ woT,
                            u16* __restrict__ w1T, u16* __restrict__ w2T,
                            float* __restrict__ bqkv,
                            float* __restrict__ bn1sc, float* __restrict__ bn1sh,
                            float* __restrict__ bn2sc, float* __restrict__ bn2sh) {
    int idx = blockIdx.x * 256 + threadIdx.x;
    if (idx < 196608) {                       // wqkvT [768][256]
        int n = idx >> 8, k = idx & 255;
        float v;
        if (n < 256)      v = wq[k * 256 + n];
        else if (n < 512) v = wk[k * 256 + (n - 256)] * C1F;
        else              v = wv[k * 256 + (n - 512)];
        wqkvT[idx] = f2bf(v);
    } else if (idx < 262144) {                // woT [256][256]
        int i = idx - 196608; int n = i >> 8, k = i & 255;
        woT[i] = f2bf(wo[k * 256 + n]);
    } else if (idx < 524288) {                // w1T [1024][256]
        int i = idx - 262144; int n = i >> 8, k = i & 255;
        w1T[i] = f2bf(w1[k * 1024 + n]);
    } else if (idx < 786432) {                // w2T [256][1024]
        int i = idx - 524288; int n = i >> 10, k = i & 1023;
        w2T[i] = f2bf(w2[k * 256 + n]);
    } else if (idx < 787200) {                // bqkv [768]
        int i = idx - 786432;
        bqkv[i] = (i < 256) ? bq[i] : (i < 512 ? bk[i - 256] * C1F : bv[i - 512]);
    } else if (idx < 787456) {                // bn1 sc/sh
        int i = idx - 787200;
        float sc = g1[i] * rsqrtf(v1[i] + EPS);
        bn1sc[i] = sc; bn1sh[i] = b1[i] - m1[i] * sc;
    } else if (idx < 787712) {                // bn2 sc/sh
        int i = idx - 787456;
        float sc = g2[i] * rsqrtf(v2[i] + EPS);
        bn2sc[i] = sc; bn2sh[i] = b2[i] - m2[i] * sc;
    }
}

// ---------------------------------------------------------------------------
// bn1: h = bn1(x) -> bf16 [8192][256]
// ---------------------------------------------------------------------------
__global__ void bn1_kernel(const float* __restrict__ x, const float* __restrict__ sc,
                           const float* __restrict__ sh, u16* __restrict__ h) {
    int idx = blockIdx.x * 256 + threadIdx.x;
    int base = idx * 4;
    int c = base & 255;
    float4 xv = *(const float4*)(x + base);
    float4 s4 = *(const float4*)(sc + c);
    float4 h4 = *(const float4*)(sh + c);
    ushort4 pk;
    pk.x = f2bf(fmaf(xv.x, s4.x, h4.x));
    pk.y = f2bf(fmaf(xv.y, s4.y, h4.y));
    pk.z = f2bf(fmaf(xv.z, s4.z, h4.z));
    pk.w = f2bf(fmaf(xv.w, s4.w, h4.w));
    *(ushort4*)(h + base) = pk;
}

// ---------------------------------------------------------------------------
// 64x64-tile staged GEMM (occupancy-first): C[M,N] = A[M,K] @ Bt[N,K]^T.
// 4 row-stacked waves (wave w: rows w*16..+15, all 64 cols). Single-buffered
// 16 KB LDS; A/B tiles via global_load_lds width=16 + XOR chunk swizzle.
// EPI 0: qkv (col<512: +bias->row-major; col>=512: +bias->vT transposed)
// EPI 1: +bias+resid->f32 x1 AND bn2->bf16 h2
// EPI 2: gelu->bf16 | EPI 3: +resid->f32
// ---------------------------------------------------------------------------
template <int EPI>
__global__ __launch_bounds__(256) void gemm64(
        const u16* __restrict__ A, const u16* __restrict__ Bt,
        int M, int N, int K,
        const float* __restrict__ bias, const float* __restrict__ resid,
        float* __restrict__ out_f32, u16* __restrict__ out_bf,
        u16* __restrict__ out_vt,
        const float* __restrict__ b2sc, const float* __restrict__ b2sh) {
    __shared__ u16 abuf[64 * 64];    // 8 KB
    __shared__ u16 bbuf[64 * 64];    // 8 KB
    const int t = threadIdx.x;
    const int w = t >> 6, lane = t & 63;
    const int l = lane & 15, Q = lane >> 4;
    const int m0 = blockIdx.x * 64;
    const int n0 = blockIdx.y * 64;

    f32x4 acc[4];
#pragma unroll
    for (int nt = 0; nt < 4; ++nt) acc[nt] = (f32x4){0.f, 0.f, 0.f, 0.f};

    for (int k0 = 0; k0 < K; k0 += 64) {
        // stage A and B tiles (512 chunks of 16B each)
#pragma unroll
        for (int j = 0; j < 2; ++j) {
            int idx = j * 256 + t;
            int r = idx >> 3, c8 = idx & 7;
            int sc = c8 ^ (r & 7);
            async_cp16(A + (size_t)(m0 + r) * K + k0 + sc * 8, abuf + idx * 8);
        }
#pragma unroll
        for (int j = 0; j < 2; ++j) {
            int idx = j * 256 + t;
            int r = idx >> 3, c8 = idx & 7;
            int sc = c8 ^ (r & 7);
            async_cp16(Bt + (size_t)(n0 + r) * K + k0 + sc * 8, bbuf + idx * 8);
        }
        __syncthreads();   // vmcnt drained: tiles ready
#pragma unroll
        for (int kd = 0; kd < 2; ++kd) {
            int ar = w * 16 + l;
            short8 afr = *(const short8*)(abuf + ar * 64 + (((kd * 4 + Q) ^ (ar & 7))) * 8);
#pragma unroll
            for (int nt = 0; nt < 4; ++nt) {
                int r = nt * 16 + l;
                short8 bfr = *(const short8*)(bbuf + r * 64 + (((kd * 4 + Q) ^ (r & 7))) * 8);
                acc[nt] = __builtin_amdgcn_mfma_f32_16x16x32_bf16(afr, bfr, acc[nt], 0, 0, 0);
            }
        }
        __syncthreads();   // all waves done before next stage overwrites
    }

#pragma unroll
    for (int nt = 0; nt < 4; ++nt) {
        int col = n0 + nt * 16 + l;
        int row0 = m0 + w * 16 + Q * 4;
        if (EPI == 0) {
            float b = bias[col];
            if (col < 512) {
#pragma unroll
                for (int r = 0; r < 4; ++r)
                    out_bf[(size_t)(row0 + r) * 512 + col] = f2bf(acc[nt][r] + b);
            } else {
                ushort4 pk;
                pk.x = f2bf(acc[nt][0] + b);
                pk.y = f2bf(acc[nt][1] + b);
                pk.z = f2bf(acc[nt][2] + b);
                pk.w = f2bf(acc[nt][3] + b);
                *(ushort4*)(out_vt + (size_t)(col - 512) * 8192 + row0) = pk;
            }
        } else {
#pragma unroll
            for (int r = 0; r < 4; ++r) {
                int row = row0 + r;
                float val = acc[nt][r];
                size_t oidx = (size_t)row * N + col;
                if (EPI == 1) {
                    val += bias[col] + resid[oidx];
                    out_f32[oidx] = val;
                    out_bf[oidx] = f2bf(fmaf(val, b2sc[col], b2sh[col]));
                } else if (EPI == 2) {
                    float gl = 0.5f * val * (1.f + erff(val * 0.70710678118654752f));
                    out_bf[oidx] = f2bf(gl);
                } else {
                    out_f32[oidx] = val + resid[oidx];
                }
            }
        }
    }
}

// ---------------------------------------------------------------------------
// Flash attention v5: S^T form, no-max softmax, P^T -> PV via 16x16x16 MFMA
// identity layout. Single-buffered 16 KB K/V LDS; sp=8 splits -> 2048 WGs
// (8 WG/CU). Wave = 32 q; WG = 128 q; grid (16 qt, 16 bh, 8 sp). bf16 partials.
// ---------------------------------------------------------------------------
static __device__ __forceinline__ void stage_tiles(const u16* kglob, const u16* vglob,
                                                   u16* kdst, u16* vdst,
                                                   int w, int lane, int kt) {
#pragma unroll
    for (int j = 0; j < 2; ++j) {
        int cw = (w * 2 + j) * 64 + lane;     // chunk 0..511
        int r = cw >> 3;                       // tile row 0..63
        int c = (cw & 7) ^ (r & 7);            // swizzled source chunk
        async_cp16(kglob + ((size_t)(kt * 64 + r)) * 512 + c * 8, kdst + (w * 2 + j) * 512);
        async_cp16(vglob + ((size_t)r) * 8192 + kt * 64 + c * 8, vdst + (w * 2 + j) * 512);
    }
}

__global__ __launch_bounds__(256) void attn_kernel(const u16* __restrict__ qk,
                                                   const u16* __restrict__ vT,
                                                   u16* __restrict__ opart,
                                                   float* __restrict__ lpart) {
    __shared__ u16 kbuf[4096];        // 64x64 bf16, 8-chunk XOR swizzle
    __shared__ u16 vbuf[4096];
    const int t = threadIdx.x;
    const int w = t >> 6, lane = t & 63;
    const int l = lane & 15, Q = lane >> 4;
    const int qt = blockIdx.x;        // 0..15
    const int bh = blockIdx.y;        // 0..15
    const int sp = blockIdx.z;        // 0..7 (256 s each)
    const int bb = bh >> 2, hd = bh & 3;
    const size_t rowbase = (size_t)bb * 2048;
    const int q0 = qt * 128 + w * 32;

    // Q B-frags (16x16x32), held for whole loop
    short8 qf[2][2];
#pragma unroll
    for (int qg = 0; qg < 2; ++qg)
#pragma unroll
        for (int kd = 0; kd < 2; ++kd)
            qf[qg][kd] = *(const short8*)(qk + (rowbase + q0 + qg * 16 + l) * 512
                                          + hd * 64 + kd * 32 + Q * 8);

    f32x4 o[2][4];
#pragma unroll
    for (int qg = 0; qg < 2; ++qg)
#pragma unroll
        for (int dt = 0; dt < 4; ++dt) o[qg][dt] = (f32x4){0.f, 0.f, 0.f, 0.f};
    float lacc[2] = {0.f, 0.f};

    const u16* kglob = qk + (rowbase + sp * 256) * 512 + 256 + hd * 64;      // row stride 512
    const u16* vglob = vT + ((size_t)(hd * 64)) * 8192 + rowbase + sp * 256; // row stride 8192

    for (int kt = 0; kt < 4; ++kt) {
        stage_tiles(kglob, vglob, kbuf, vbuf, w, lane, kt);
        __syncthreads();              // drains vmcnt: tile ready

        // S^T = K.Q^T -> exp2 -> pack. pf[qg][st] = B-frag for 16x16x16 PV.
        union { u32 u[2]; short4v s4; } pf[2][4];
#pragma unroll
        for (int st = 0; st < 4; ++st) {
            int r = st * 16 + l;
            short8 kf0 = *(const short8*)(kbuf + r * 64 + ((Q) ^ (r & 7)) * 8);
            short8 kf1 = *(const short8*)(kbuf + r * 64 + ((4 + Q) ^ (r & 7)) * 8);
#pragma unroll
            for (int qg = 0; qg < 2; ++qg) {
                f32x4 s = (f32x4){0.f, 0.f, 0.f, 0.f};
                s = __builtin_amdgcn_mfma_f32_16x16x32_bf16(kf0, qf[qg][0], s, 0, 0, 0);
                s = __builtin_amdgcn_mfma_f32_16x16x32_bf16(kf1, qf[qg][1], s, 0, 0, 0);
                float p0 = exp2f(fminf(s[0], 100.f));
                float p1 = exp2f(fminf(s[1], 100.f));
                float p2 = exp2f(fminf(s[2], 100.f));
                float p3 = exp2f(fminf(s[3], 100.f));
                lacc[qg] += (p0 + p1) + (p2 + p3);
                pf[qg][st].u[0] = pack_bf2(p0, p1);
                pf[qg][st].u[1] = pack_bf2(p2, p3);
            }
        }

        // O^T += V^T . P^T : 4 chunks of K=16, A = V^T from LDS (b64),
        // B = pf (identity C->B layout for 16x16x16)
#pragma unroll
        for (int c = 0; c < 4; ++c) {
#pragma unroll
            for (int dt = 0; dt < 4; ++dt) {
                int r = dt * 16 + l;
                int slot = (2 * c + (Q >> 1)) ^ (r & 7);
                short4v vf = *(const short4v*)(vbuf + r * 64 + slot * 8 + (Q & 1) * 4);
                o[0][dt] = MFMA16(vf, pf[0][c].s4, o[0][dt]);
                o[1][dt] = MFMA16(vf, pf[1][c].s4, o[1][dt]);
            }
        }
        __syncthreads();              // all waves done before restage
    }

    // epilogue: reduce l across quads; bf16 partials
#pragma unroll
    for (int qg = 0; qg < 2; ++qg) {
        float v = lacc[qg];
        v += __shfl_xor(v, 16);
        v += __shfl_xor(v, 32);
        lacc[qg] = v;
    }
    u16* ob = opart + (((size_t)sp * 16 + bh) * 2048 + q0) * 64;
#pragma unroll
    for (int qg = 0; qg < 2; ++qg)
#pragma unroll
        for (int dt = 0; dt < 4; ++dt) {
            ushort4 pk;
            pk.x = f2bf(o[qg][dt][0]);
            pk.y = f2bf(o[qg][dt][1]);
            pk.z = f2bf(o[qg][dt][2]);
            pk.w = f2bf(o[qg][dt][3]);
            *(ushort4*)(ob + (size_t)(qg * 16 + l) * 64 + dt * 16 + Q * 4) = pk;
        }
    if (Q == 0) {
        size_t lb = ((size_t)sp * 16 + bh) * 2048 + q0;
        lpart[lb + l] = lacc[0];
        lpart[lb + 16 + l] = lacc[1];
    }
}

// ---------------------------------------------------------------------------
// combine: ctx[b*2048+s][h*64+d] = sum_sp(o_sp) / sum_sp(l_sp) -> bf16
// ---------------------------------------------------------------------------
__global__ void combine_kernel(const u16* __restrict__ opart,
                               const float* __restrict__ lpart,
                               u16* __restrict__ ctx) {
    int idx = blockIdx.x * 256 + threadIdx.x;
    int e = idx * 4;
    int row = e >> 8, col = e & 255;
    int b = row >> 11, s = row & 2047, h = col >> 6, d = col & 63;
    float a0 = 0.f, a1 = 0.f, a2 = 0.f, a3 = 0.f, lsum = 0.f;
#pragma unroll
    for (int sp = 0; sp < 8; ++sp) {
        size_t pb = (((size_t)sp * 16 + b * 4 + h) * 2048 + s) * 64 + d;
        ushort4 ov = *(const ushort4*)(opart + pb);
        a0 += bf2f(ov.x); a1 += bf2f(ov.y); a2 += bf2f(ov.z); a3 += bf2f(ov.w);
        lsum += lpart[((size_t)sp * 16 + b * 4 + h) * 2048 + s];
    }
    float li = 1.0f / lsum;
    ushort4 pk;
    pk.x = f2bf(a0 * li);
    pk.y = f2bf(a1 * li);
    pk.z = f2bf(a2 * li);
    pk.w = f2bf(a3 * li);
    *(ushort4*)(ctx + e) = pk;
}

// ---------------------------------------------------------------------------
extern "C" void kernel_launch(void* const* d_in, const int* in_sizes, int n_in,
                              void* d_out, int out_size, void* d_ws, size_t ws_size,
                              hipStream_t stream) {
    (void)in_sizes; (void)n_in; (void)out_size; (void)ws_size;
    const float* x  = (const float*)d_in[0];
    const float* g1 = (const float*)d_in[1];
    const float* b1 = (const float*)d_in[2];
    const float* m1 = (const float*)d_in[3];
    const float* v1 = (const float*)d_in[4];
    const float* wq = (const float*)d_in[5];
    const float* bq = (const float*)d_in[6];
    const float* wk = (const float*)d_in[7];
    const float* bk = (const float*)d_in[8];
    const float* wv = (const float*)d_in[9];
    const float* bv = (const float*)d_in[10];
    const float* wo = (const float*)d_in[11];
    const float* bo = (const float*)d_in[12];
    const float* g2 = (const float*)d_in[13];
    const float* b2 = (const float*)d_in[14];
    const float* m2 = (const float*)d_in[15];
    const float* v2 = (const float*)d_in[16];
    const float* w1 = (const float*)d_in[17];
    const float* w2 = (const float*)d_in[18];

    char* ws = (char*)d_ws;
    u16*   qkb    = (u16*)(ws + (0ull << 20));    // [8192][512] bf16, 8 MB
    u16*   vTb    = (u16*)(ws + (8ull << 20));    // [256][8192] bf16, 4 MB
    u16*   h_buf  = (u16*)(ws + (12ull << 20));   // [8192][256] bf16, 4 MB
    u16*   ctx    = (u16*)(ws + (16ull << 20));   // [8192][256] bf16, 4 MB
    float* x1     = (float*)(ws + (20ull << 20)); // [8192][256] f32, 8 MB
    u16*   h2     = (u16*)(ws + (28ull << 20));   // [8192][256] bf16, 4 MB
    u16*   gbuf   = (u16*)(ws + (32ull << 20));   // [8192][1024] bf16, 16 MB
    u16*   opart  = (u16*)(ws + (48ull << 20));   // [8][16][2048][64] bf16, 32 MB
    float* lpart  = (float*)(ws + (80ull << 20)); // [8][16][2048] f32, 1 MB
    u16*   wqkvT  = (u16*)(ws + (81ull << 20));   // [768][256] bf16
    u16*   woT    = (u16*)(ws + (82ull << 20));   // [256][256]
    u16*   w1T    = (u16*)(ws + (83ull << 20));   // [1024][256]
    u16*   w2T    = (u16*)(ws + (84ull << 20));   // [256][1024]
    float* bqkv   = (float*)(ws + (85ull << 20)); // [768]
    float* bn1sc  = (float*)(ws + (85ull << 20) + 4096);
    float* bn1sh  = (float*)(ws + (85ull << 20) + 8192);
    float* bn2sc  = (float*)(ws + (85ull << 20) + 12288);
    float* bn2sh  = (float*)(ws + (85ull << 20) + 16384);
    float* out    = (float*)d_out;

    prep_kernel<<<3077, 256, 0, stream>>>(wq, wk, wv, wo, w1, w2, bq, bk, bv,
                                          g1, b1, m1, v1, g2, b2, m2, v2,
                                          wqkvT, woT, w1T, w2T, bqkv,
                                          bn1sc, bn1sh, bn2sc, bn2sh);
    bn1_kernel<<<2048, 256, 0, stream>>>(x, bn1sc, bn1sh, h_buf);
    // QKV projection (q|k row-major into qkb; v transposed into vTb)
    gemm64<0><<<dim3(128, 12), 256, 0, stream>>>(
        h_buf, wqkvT, 8192, 768, 256, bqkv, nullptr, nullptr, qkb, vTb, nullptr, nullptr);
    // attention partials + combine
    attn_kernel<<<dim3(16, 16, 8), 256, 0, stream>>>(qkb, vTb, opart, lpart);
    combine_kernel<<<2048, 256, 0, stream>>>(opart, lpart, ctx);
    // O projection + residual + bn2
    gemm64<1><<<dim3(128, 4), 256, 0, stream>>>(
        ctx, woT, 8192, 256, 256, bo, x, x1, h2, nullptr, bn2sc, bn2sh);
    // FFN1 + gelu
    gemm64<2><<<dim3(128, 16), 256, 0, stream>>>(
        h2, w1T, 8192, 1024, 256, nullptr, nullptr, nullptr, gbuf, nullptr, nullptr, nullptr);
    // FFN2 + residual -> out
    gemm64<3><<<dim3(128, 4), 256, 0, stream>>>(
        gbuf, w2T, 8192, 256, 1024, nullptr, x1, out, nullptr, nullptr, nullptr, nullptr);
}